// Round 1
// 544.559 us; speedup vs baseline: 1.2113x; 1.2113x over previous
//
#include <hip/hip_runtime.h>
#include <hip/hip_fp16.h>
#include <cstdint>

#define M_TOK 8192
#define K_IN  4096
#define N_OUT 4096
#define RANK  64
#define KSPLIT 8          // k_t split-K factor; chunk = K_IN/KSPLIT = 512
#define LDA_P 4160        // padded K: 4096 main + 64 adapter
#define NT_P  65          // 4160 / 64 K-tiles

typedef _Float16 f16x8 __attribute__((ext_vector_type(8)));
typedef _Float16 f16x4 __attribute__((ext_vector_type(4)));
typedef float    f32x4 __attribute__((ext_vector_type(4)));

__device__ __forceinline__ void gld_lds16(const void* g, void* l) {
    __builtin_amdgcn_global_load_lds(
        (const __attribute__((address_space(1))) void*)g,
        (__attribute__((address_space(3))) void*)l,
        16, 0, 0);
}

// ---------------------------------------------------------------------------
// Conversion kernels
// ---------------------------------------------------------------------------
__global__ void k_cvt_f32_f16(const float4* __restrict__ in,
                              f16x4* __restrict__ out, int n4) {
    int i = blockIdx.x * 256 + threadIdx.x;
    if (i >= n4) return;
    float4 v = in[i];
    f16x4 r;
    r[0] = (_Float16)v.x; r[1] = (_Float16)v.y;
    r[2] = (_Float16)v.z; r[3] = (_Float16)v.w;
    out[i] = r;
}

// WU[o][k] = f16(Q[o][k]*scales[o]) for k<4096 (row stride LDA_P).
__global__ void k_cvt_w8(const int4* __restrict__ Q, const float* __restrict__ s,
                         _Float16* __restrict__ WU) {
    int i = blockIdx.x * 256 + threadIdx.x;   // group-of-8 index, < 2097152
    float sc = s[i >> 9];                     // (i*8)/4096
    int4 q0 = Q[2 * i], q1 = Q[2 * i + 1];
    f16x8 r;
    r[0] = (_Float16)(q0.x * sc); r[1] = (_Float16)(q0.y * sc);
    r[2] = (_Float16)(q0.z * sc); r[3] = (_Float16)(q0.w * sc);
    r[4] = (_Float16)(q1.x * sc); r[5] = (_Float16)(q1.y * sc);
    r[6] = (_Float16)(q1.z * sc); r[7] = (_Float16)(q1.w * sc);
    *(f16x8*)(WU + (size_t)(i >> 9) * LDA_P + (size_t)(i & 511) * 8) = r;
}

// WU[o][4096+r] = f16(U[o][r])  (adapter tail columns)
__global__ void k_cvt_u(const float* __restrict__ U, _Float16* __restrict__ WU) {
    int i = blockIdx.x * 256 + threadIdx.x;   // i < 4096*64/8
    int o = i >> 3, c = (i & 7) * 8;
    const float4* up = (const float4*)(U + (size_t)o * RANK + c);
    float4 v0 = up[0], v1 = up[1];
    f16x8 r;
    r[0] = (_Float16)v0.x; r[1] = (_Float16)v0.y;
    r[2] = (_Float16)v0.z; r[3] = (_Float16)v0.w;
    r[4] = (_Float16)v1.x; r[5] = (_Float16)v1.y;
    r[6] = (_Float16)v1.z; r[7] = (_Float16)v1.w;
    *(f16x8*)(WU + (size_t)o * LDA_P + 4096 + c) = r;
}

// ---------------------------------------------------------------------------
// Fused: x fp32 -> XT f16 (cols 0..4095, row stride LDA_P)  +  partial
// t = x @ D.T (split-K). Grid: (128 row-blocks, 8 k-chunks), 256 thr.
// ---------------------------------------------------------------------------
__global__ __launch_bounds__(256)
void k_t_fused(const float* __restrict__ X, const _Float16* __restrict__ Dh,
               _Float16* __restrict__ XT, float* __restrict__ T32) {
    __shared__ _Float16 Xs[64 * 32];
    __shared__ _Float16 Ds[64 * 32];
    const int tid = threadIdx.x, wave = tid >> 6, lane = tid & 63;
    const int row0 = blockIdx.x * 64;
    const int kbase = blockIdx.y * (K_IN / KSPLIT);
    const int lr = tid >> 2, lk = (tid & 3) * 8;     // x-load: row, k-offset
    const int rr = lane >> 2, c8 = (lane & 3) * 8;   // gld_lds lane mapping
    const int fm = lane & 15, fk = (lane >> 4) * 8;  // MFMA fragment mapping
    f32x4 acc[4] = {};

    for (int kk = 0; kk < K_IN / KSPLIT; kk += 32) {
        const int k0 = kbase + kk;
        const float* gx = X + (size_t)(row0 + lr) * K_IN + k0 + lk;
        float4 v0 = *(const float4*)gx;
        float4 v1 = *(const float4*)(gx + 4);
        f16x8 h;
        h[0] = (_Float16)v0.x; h[1] = (_Float16)v0.y;
        h[2] = (_Float16)v0.z; h[3] = (_Float16)v0.w;
        h[4] = (_Float16)v1.x; h[5] = (_Float16)v1.y;
        h[6] = (_Float16)v1.z; h[7] = (_Float16)v1.w;
        *(f16x8*)(XT + (size_t)(row0 + lr) * LDA_P + k0 + lk) = h;
        *(f16x8*)&Xs[lr * 32 + lk] = h;
        gld_lds16(Dh + (size_t)(wave * 16 + rr) * K_IN + k0 + c8,
                  Ds + wave * 16 * 32);
        __syncthreads();
        f16x8 a = *(const f16x8*)&Xs[(wave * 16 + fm) * 32 + fk];
#pragma unroll
        for (int n = 0; n < 4; n++) {
            f16x8 b = *(const f16x8*)&Ds[(n * 16 + fm) * 32 + fk];
            acc[n] = __builtin_amdgcn_mfma_f32_16x16x32_f16(a, b, acc[n], 0, 0, 0);
        }
        __syncthreads();
    }
#pragma unroll
    for (int n = 0; n < 4; n++)
#pragma unroll
        for (int r = 0; r < 4; r++) {
            int row = row0 + wave * 16 + (lane >> 4) * 4 + r;
            int col = n * 16 + (lane & 15);
            T32[((size_t)blockIdx.y * M_TOK + row) * RANK + col] = acc[n][r];
        }
}

// XT[row][4096+r] = f16( sum_c T32[c][row][r] )
__global__ void k_reduce_t(const float* __restrict__ T32,
                           _Float16* __restrict__ XT) {
    int i = blockIdx.x * 256 + threadIdx.x;   // i < 8192*64
    float s = 0.f;
#pragma unroll
    for (int c = 0; c < KSPLIT; c++)
        s += T32[(size_t)c * M_TOK * RANK + i];
    XT[(size_t)(i >> 6) * LDA_P + 4096 + (i & 63)] = (_Float16)s;
}

// ---------------------------------------------------------------------------
// Main GEMM: 256x256 tile, BK=64, 8 waves (2Mx4N), 8-phase schedule
// (T1 XCD swizzle + T2 XOR-swizzled LDS + T3/T4 counted vmcnt + T5 setprio).
// K is the padded 4160 (main 4096 + adapter 64) -> fully uniform hot loop.
//
// LDS unit map (16B units): u(row,k8) = row*8 + (k8 ^ (row&7)).
//  - ds_read_b128 frag (lane = g*16+m): consecutive 8 lanes hit 8 distinct
//    bank-quads -> conflict-free.
//  - global_load_lds dest stays linear (base + lane*16); the XOR is applied
//    to the per-lane GLOBAL source column, so each 8-lane group still reads
//    one contiguous 128B global row (coalesced).  [rule 21: both-sides swz]
//
// Region = 64 rows = 8KiB = one gld_lds call (8 waves x 8 rows).
// Per tile t (buf p), phases (mh,ks): (0,0) (0,1) (1,0) (1,1):
//   ph0: stage B0..B3(t+1)->buf q      (q freed at end of t-1)
//   ph1: stage A1,A3(t+1)->buf q;  vmcnt(8)  [forces A1,A3(t) for ph2]
//   ph2: no stage
//   ph3: stage A0,A2(t+2)->buf p (A{0,2} of p dead after ph1); vmcnt(4)
//        [forces B(t+1)+A0,A2(t+1) for next tile's ph0]
// Min landing slack 3 phases; vmcnt never drains below 4 in the loop.
// Tail tiles stage wrapped (t+k)%NT sources into provably-dead regions so
// the vmcnt counting stays uniform.
// ---------------------------------------------------------------------------
__global__ __launch_bounds__(512, 2)
void k_main(const _Float16* __restrict__ XT, const _Float16* __restrict__ WU,
            float* __restrict__ C) {
    __shared__ _Float16 lds[2][2][256 * 64];   // [buf][A,B] : 128 KiB total
    const int tid = threadIdx.x;
    const int wave = tid >> 6, lane = tid & 63;
    const int wr = wave >> 2, wc = wave & 3;        // 2M x 4N waves
    const int fm = lane & 15, g = lane >> 4;

    // bijective XCD swizzle: 512 wgs, 512 % 8 == 0
    int bs = (blockIdx.x & 7) * 64 + (blockIdx.x >> 3);
    const int bx = bs & 15, by = bs >> 4;           // 16 N-tiles, 32 M-tiles
    const int arow0 = by * 256, brow0 = bx * 256;

    // staging lane geometry (inverse-swizzled global source)
    const int srow = wave * 8 + (lane >> 3);
    const int scol = ((lane & 7) ^ (lane >> 3)) * 8;

    // swizzled ds_read offsets (f16 elements)
    const int ax0 = (g ^ (fm & 7)) * 8;             // ks=0
    const int ax1 = ((4 + g) ^ (fm & 7)) * 8;       // ks=1
    const int aRB = (wr * 128 + fm) * 64;
    const int bRB = (wc * 64 + fm) * 64;

    f32x4 acc[8][4] = {};

    auto stA = [&](int q, int r, int t) {
        gld_lds16(XT + (size_t)(arow0 + r * 64 + srow) * LDA_P + t * 64 + scol,
                  &lds[q][0][(r * 512 + wave * 64) * 8]);
    };
    auto stB = [&](int q, int r, int t) {
        gld_lds16(WU + (size_t)(brow0 + r * 64 + srow) * LDA_P + t * 64 + scol,
                  &lds[q][1][(r * 512 + wave * 64) * 8]);
    };

#define VMC(n) asm volatile("s_waitcnt vmcnt(" #n ")" ::: "memory")
#define PHASE(P, MH, KS, STG, VM) do {                                        \
    const _Float16* Ab = &lds[P][0][0];                                       \
    const _Float16* Bb = &lds[P][1][0];                                       \
    const int ax = (KS ? ax1 : ax0);                                          \
    f16x8 a[4], b[4];                                                         \
    _Pragma("unroll")                                                         \
    for (int m = 0; m < 4; ++m)                                               \
        a[m] = *(const f16x8*)&Ab[aRB + MH * 4096 + m * 1024 + ax];           \
    _Pragma("unroll")                                                         \
    for (int n = 0; n < 4; ++n)                                               \
        b[n] = *(const f16x8*)&Bb[bRB + n * 1024 + ax];                       \
    STG                                                                       \
    __builtin_amdgcn_s_barrier();                                             \
    asm volatile("s_waitcnt lgkmcnt(0)" ::: "memory");                        \
    __builtin_amdgcn_s_setprio(1);                                            \
    _Pragma("unroll")                                                         \
    for (int m = 0; m < 4; ++m)                                               \
        _Pragma("unroll")                                                     \
        for (int n = 0; n < 4; ++n)                                           \
            acc[MH * 4 + m][n] = __builtin_amdgcn_mfma_f32_16x16x32_f16(      \
                a[m], b[n], acc[MH * 4 + m][n], 0, 0, 0);                     \
    __builtin_amdgcn_s_setprio(0);                                            \
    VM;                                                                       \
    __builtin_amdgcn_s_barrier();                                             \
} while (0)

#define TILE(P, T1, T2)                                                       \
    PHASE(P, 0, 0,                                                            \
          { stB(P ^ 1, 0, T1); stB(P ^ 1, 1, T1);                             \
            stB(P ^ 1, 2, T1); stB(P ^ 1, 3, T1); }, );                       \
    PHASE(P, 0, 1, { stA(P ^ 1, 1, T1); stA(P ^ 1, 3, T1); }, VMC(8));        \
    PHASE(P, 1, 0, {;}, );                                                    \
    PHASE(P, 1, 1, { stA(P, 0, T2); stA(P, 2, T2); }, VMC(4))

    // prologue: tile0 full + tile1 A{0,2}; leave {A1,A3(0), A0,A2(1)} in flight
    stA(0, 0, 0); stA(0, 2, 0);
    stB(0, 0, 0); stB(0, 1, 0); stB(0, 2, 0); stB(0, 3, 0);
    stA(0, 1, 0); stA(0, 3, 0);
    stA(1, 0, 1); stA(1, 2, 1);
    VMC(4);
    __builtin_amdgcn_s_barrier();

#pragma unroll 1
    for (int t = 0; t < NT_P - 1; t += 2) {
        int t2b = t + 3;
        if (t2b >= NT_P) t2b = 0;                  // wrap: dead-region stage
        TILE(0, t + 1, t + 2);
        TILE(1, t + 2, t2b);
    }
    TILE(0, 0, 1);                                 // tile 64; stages wrap (dead)

#undef TILE
#undef PHASE
#undef VMC

    // epilogue: C/D layout col=lane&15, row=(lane>>4)*4+reg
#pragma unroll
    for (int mi = 0; mi < 8; ++mi) {
        const int row = arow0 + wr * 128 + mi * 16 + g * 4;
#pragma unroll
        for (int n = 0; n < 4; ++n) {
            const int col = brow0 + wc * 64 + n * 16 + fm;
            float* cp = C + (size_t)row * N_OUT + col;
#pragma unroll
            for (int r = 0; r < 4; ++r)
                cp[(size_t)r * N_OUT] = acc[mi][n][r];
        }
    }
}

// ---------------------------------------------------------------------------
// Naive fp32 fallback (ws too small)
// ---------------------------------------------------------------------------
__global__ void fb_t(const float* __restrict__ x, const float* __restrict__ Dm,
                     float* __restrict__ t) {
    int n = blockIdx.x, r = threadIdx.x;
    const float* xr = x + (size_t)n * K_IN;
    const float* dr = Dm + (size_t)r * K_IN;
    float s = 0.f;
    for (int k = 0; k < K_IN; k++) s += xr[k] * dr[k];
    t[n * RANK + r] = s;
}

__global__ void fb_main(const float* __restrict__ x, const float* __restrict__ scales,
                        const float* __restrict__ U, const int* __restrict__ Q,
                        const float* __restrict__ t, float* __restrict__ out) {
    size_t i = (size_t)blockIdx.x * 256 + threadIdx.x;
    int n = (int)(i >> 12), o = (int)(i & 4095);
    const float* xr = x + (size_t)n * K_IN;
    const int* qr = Q + (size_t)o * K_IN;
    float s = 0.f;
    for (int k = 0; k < K_IN; k++) s += xr[k] * (float)qr[k];
    float a = 0.f;
    const float* tr = t + (size_t)n * RANK;
    const float* ur = U + (size_t)o * RANK;
    for (int r = 0; r < RANK; r++) a += tr[r] * ur[r];
    out[i] = scales[o] * s + a;
}

// ---------------------------------------------------------------------------
extern "C" void kernel_launch(void* const* d_in, const int* in_sizes, int n_in,
                              void* d_out, int out_size, void* d_ws, size_t ws_size,
                              hipStream_t stream) {
    const float* x      = (const float*)d_in[0];
    const float* scales = (const float*)d_in[1];
    const float* U      = (const float*)d_in[2];
    const float* D      = (const float*)d_in[3];
    const int*   Q      = (const int*)d_in[4];
    float* out = (float*)d_out;

    const size_t SZ_XT  = (size_t)M_TOK * LDA_P * 2;
    const size_t SZ_WU  = (size_t)N_OUT * LDA_P * 2;
    const size_t SZ_D   = (size_t)RANK * K_IN * 2;
    const size_t SZ_T32 = (size_t)KSPLIT * M_TOK * RANK * 4;
    const size_t NEED   = SZ_XT + SZ_WU + SZ_D + SZ_T32;

    if (ws_size >= NEED) {
        char* w = (char*)d_ws;
        _Float16* XT  = (_Float16*)w; w += SZ_XT;
        _Float16* WU  = (_Float16*)w; w += SZ_WU;
        _Float16* Dh  = (_Float16*)w; w += SZ_D;
        float*    T32 = (float*)w;

        k_cvt_f32_f16<<<256, 256, 0, stream>>>((const float4*)D, (f16x4*)Dh,
                                               RANK * K_IN / 4);
        k_t_fused<<<dim3(M_TOK / 64, KSPLIT), 256, 0, stream>>>(x, Dh, XT, T32);
        k_reduce_t<<<M_TOK * RANK / 256, 256, 0, stream>>>(T32, XT);
        k_cvt_w8<<<N_OUT * K_IN / 8 / 256, 256, 0, stream>>>((const int4*)Q,
                                                             scales, WU);
        k_cvt_u<<<N_OUT * RANK / 8 / 256, 256, 0, stream>>>(U, WU);
        k_main<<<512, 512, 0, stream>>>(XT, WU, out);
    } else {
        float* t32 = (float*)d_ws;
        fb_t<<<M_TOK, RANK, 0, stream>>>(x, D, t32);
        fb_main<<<(int)((size_t)M_TOK * N_OUT / 256), 256, 0, stream>>>(
            x, scales, U, Q, t32, out);
    }
}

// Round 2
// 523.270 us; speedup vs baseline: 1.2606x; 1.0407x over previous
//
#include <hip/hip_runtime.h>
#include <hip/hip_fp16.h>
#include <cstdint>

#define M_TOK 8192
#define K_IN  4096
#define N_OUT 4096
#define RANK  64
#define KSPLIT 8          // k_t split-K factor; chunk = K_IN/KSPLIT = 512
#define LDA_P 4160        // padded K: 4096 main + 64 adapter
#define NT_P  65          // 4160 / 64 K-tiles

typedef _Float16 f16x8 __attribute__((ext_vector_type(8)));
typedef _Float16 f16x4 __attribute__((ext_vector_type(4)));
typedef float    f32x4 __attribute__((ext_vector_type(4)));

__device__ __forceinline__ void gld_lds16(const void* g, void* l) {
    __builtin_amdgcn_global_load_lds(
        (const __attribute__((address_space(1))) void*)g,
        (__attribute__((address_space(3))) void*)l,
        16, 0, 0);
}

// ---------------------------------------------------------------------------
// Conversion kernels
// ---------------------------------------------------------------------------
__global__ void k_cvt_f32_f16(const float4* __restrict__ in,
                              f16x4* __restrict__ out, int n4) {
    int i = blockIdx.x * 256 + threadIdx.x;
    if (i >= n4) return;
    float4 v = in[i];
    f16x4 r;
    r[0] = (_Float16)v.x; r[1] = (_Float16)v.y;
    r[2] = (_Float16)v.z; r[3] = (_Float16)v.w;
    out[i] = r;
}

// Pure streaming x fp32 -> XT f16 (cols 0..4095, row stride LDA_P)
__global__ __launch_bounds__(256)
void k_cvt_x(const float4* __restrict__ X, _Float16* __restrict__ XT) {
    for (int i = blockIdx.x * 256 + threadIdx.x; i < M_TOK * K_IN / 8;
         i += gridDim.x * 256) {
        float4 v0 = X[2 * i], v1 = X[2 * i + 1];
        f16x8 h;
        h[0] = (_Float16)v0.x; h[1] = (_Float16)v0.y;
        h[2] = (_Float16)v0.z; h[3] = (_Float16)v0.w;
        h[4] = (_Float16)v1.x; h[5] = (_Float16)v1.y;
        h[6] = (_Float16)v1.z; h[7] = (_Float16)v1.w;
        *(f16x8*)(XT + (size_t)(i >> 9) * LDA_P + (size_t)(i & 511) * 8) = h;
    }
}

// WU[o][k] = f16(Q[o][k]*scales[o]) for k<4096 (row stride LDA_P).
__global__ void k_cvt_w8(const int4* __restrict__ Q, const float* __restrict__ s,
                         _Float16* __restrict__ WU) {
    int i = blockIdx.x * 256 + threadIdx.x;   // group-of-8 index, < 2097152
    float sc = s[i >> 9];                     // (i*8)/4096
    int4 q0 = Q[2 * i], q1 = Q[2 * i + 1];
    f16x8 r;
    r[0] = (_Float16)(q0.x * sc); r[1] = (_Float16)(q0.y * sc);
    r[2] = (_Float16)(q0.z * sc); r[3] = (_Float16)(q0.w * sc);
    r[4] = (_Float16)(q1.x * sc); r[5] = (_Float16)(q1.y * sc);
    r[6] = (_Float16)(q1.z * sc); r[7] = (_Float16)(q1.w * sc);
    *(f16x8*)(WU + (size_t)(i >> 9) * LDA_P + (size_t)(i & 511) * 8) = r;
}

// WU[o][4096+r] = f16(U[o][r])  (adapter tail columns)
__global__ void k_cvt_u(const float* __restrict__ U, _Float16* __restrict__ WU) {
    int i = blockIdx.x * 256 + threadIdx.x;   // i < 4096*64/8
    int o = i >> 3, c = (i & 7) * 8;
    const float4* up = (const float4*)(U + (size_t)o * RANK + c);
    float4 v0 = up[0], v1 = up[1];
    f16x8 r;
    r[0] = (_Float16)v0.x; r[1] = (_Float16)v0.y;
    r[2] = (_Float16)v0.z; r[3] = (_Float16)v0.w;
    r[4] = (_Float16)v1.x; r[5] = (_Float16)v1.y;
    r[6] = (_Float16)v1.z; r[7] = (_Float16)v1.w;
    *(f16x8*)(WU + (size_t)o * LDA_P + 4096 + c) = r;
}

// ---------------------------------------------------------------------------
// Skinny adapter GEMM: T32[kc] += Xh[64-row tile] @ Dh.T over 512-wide K chunk.
// Async gld_lds double-buffer, XOR-swizzled LDS (same algebra as k_main).
// Grid (128, KSPLIT), 256 thr (4 waves; wave w owns output rows w*16..w*16+15).
// ---------------------------------------------------------------------------
__global__ __launch_bounds__(256)
void k_t(const _Float16* __restrict__ Xh, const _Float16* __restrict__ Dh,
         float* __restrict__ T32) {
    __shared__ _Float16 Xs[2][64 * 64];
    __shared__ _Float16 Ds[2][64 * 64];
    const int tid = threadIdx.x, wave = tid >> 6, lane = tid & 63;
    const int row0 = blockIdx.x * 64;
    const int kbase = blockIdx.y * (K_IN / KSPLIT);
    const int srow8 = lane >> 3;                     // 0..7 within 8-row slab
    const int scol = ((lane & 7) ^ srow8) * 8;       // inverse-swizzled source
    const int fm = lane & 15, g = lane >> 4;
    const int ax0 = (g ^ (fm & 7)) * 8;
    const int ax1 = ((4 + g) ^ (fm & 7)) * 8;
    f32x4 acc[4] = {};

    auto stage = [&](int buf, int it) {
        const int k0 = kbase + it * 64;
#pragma unroll
        for (int c = 0; c < 2; ++c) {
            int slab = wave * 2 + c;                 // 8 rows per call
            gld_lds16(Xh + (size_t)(row0 + slab * 8 + srow8) * LDA_P + k0 + scol,
                      &Xs[buf][slab * 8 * 64]);
            gld_lds16(Dh + (size_t)(slab * 8 + srow8) * K_IN + k0 + scol,
                      &Ds[buf][slab * 8 * 64]);
        }
    };

    stage(0, 0);
    __syncthreads();                                  // drains vmcnt(0)
#pragma unroll 1
    for (int it = 0; it < K_IN / KSPLIT / 64; ++it) {
        int buf = it & 1;
        if (it < K_IN / KSPLIT / 64 - 1) stage(buf ^ 1, it + 1);
        f16x8 a0 = *(const f16x8*)&Xs[buf][(wave * 16 + fm) * 64 + ax0];
        f16x8 a1 = *(const f16x8*)&Xs[buf][(wave * 16 + fm) * 64 + ax1];
#pragma unroll
        for (int n = 0; n < 4; ++n) {
            f16x8 b0 = *(const f16x8*)&Ds[buf][(n * 16 + fm) * 64 + ax0];
            acc[n] = __builtin_amdgcn_mfma_f32_16x16x32_f16(a0, b0, acc[n], 0, 0, 0);
            f16x8 b1 = *(const f16x8*)&Ds[buf][(n * 16 + fm) * 64 + ax1];
            acc[n] = __builtin_amdgcn_mfma_f32_16x16x32_f16(a1, b1, acc[n], 0, 0, 0);
        }
        __syncthreads();                              // drains next-stage DMA
    }
#pragma unroll
    for (int n = 0; n < 4; n++)
#pragma unroll
        for (int r = 0; r < 4; r++) {
            int row = row0 + wave * 16 + g * 4 + r;
            int col = n * 16 + fm;
            T32[((size_t)blockIdx.y * M_TOK + row) * RANK + col] = acc[n][r];
        }
}

// XT[row][4096+r] = f16( sum_c T32[c][row][r] )
__global__ void k_reduce_t(const float* __restrict__ T32,
                           _Float16* __restrict__ XT) {
    int i = blockIdx.x * 256 + threadIdx.x;   // i < 8192*64
    float s = 0.f;
#pragma unroll
    for (int c = 0; c < KSPLIT; c++)
        s += T32[(size_t)c * M_TOK * RANK + i];
    XT[(size_t)(i >> 6) * LDA_P + 4096 + (i & 63)] = (_Float16)s;
}

// ---------------------------------------------------------------------------
// Main GEMM: 256x256 tile, BK=64, 8 waves (2Mx4N), 8-phase schedule.
// R2 change: phase order (mh0,ks0)(mh1,ks0)(mh0,ks1)(mh1,ks1) with B-fragments
// held in registers across each ks-pair -> 24 ds_read_b128/tile (was 32);
// LDS pipe (24*12=288cy/wave) now under MFMA pipe (64*4.85=310cy/wave).
//
// Issue/tile: ph0: B0-3(t+1)->q | ph1: A1,A3(t+1)->q | ph2: - | ph3: A0,A2(t+2)->p
// Waits: ph0: VMC(6) forces A13(t)  [outstanding: B0123(t+1)=4 + A02(t+1)=2]
//        ph3: VMC(4) forces B(t+1)+A02(t+1)  [outstanding: A02(t+2)+A13(t+1)]
// Min landing slack 3 phases. Region liveness: q's B free after t-1.ph2 (last
// register B-read), q's A13 free after t-1.ph3, p's A02 free after t.ph2.
// ---------------------------------------------------------------------------
__global__ __launch_bounds__(512, 2)
void k_main(const _Float16* __restrict__ XT, const _Float16* __restrict__ WU,
            float* __restrict__ C) {
    __shared__ _Float16 lds[2][2][256 * 64];   // [buf][A,B] : 128 KiB total
    const int tid = threadIdx.x;
    const int wave = tid >> 6, lane = tid & 63;
    const int wr = wave >> 2, wc = wave & 3;        // 2M x 4N waves
    const int fm = lane & 15, g = lane >> 4;

    // bijective XCD swizzle: 512 wgs, 512 % 8 == 0
    int bs = (blockIdx.x & 7) * 64 + (blockIdx.x >> 3);
    const int bx = bs & 15, by = bs >> 4;           // 16 N-tiles, 32 M-tiles
    const int arow0 = by * 256, brow0 = bx * 256;

    // staging lane geometry (inverse-swizzled global source)
    const int srow = wave * 8 + (lane >> 3);
    const int scol = ((lane & 7) ^ (lane >> 3)) * 8;

    // swizzled ds_read offsets (f16 elements)
    const int ax0 = (g ^ (fm & 7)) * 8;             // ks=0
    const int ax1 = ((4 + g) ^ (fm & 7)) * 8;       // ks=1
    const int aRB = (wr * 128 + fm) * 64;
    const int bRB = (wc * 64 + fm) * 64;

    f32x4 acc[8][4] = {};
    f16x8 b[4];                                     // persists across ks-pair

    auto stA = [&](int q, int r, int t) {
        gld_lds16(XT + (size_t)(arow0 + r * 64 + srow) * LDA_P + t * 64 + scol,
                  &lds[q][0][(r * 512 + wave * 64) * 8]);
    };
    auto stB = [&](int q, int r, int t) {
        gld_lds16(WU + (size_t)(brow0 + r * 64 + srow) * LDA_P + t * 64 + scol,
                  &lds[q][1][(r * 512 + wave * 64) * 8]);
    };

#define VMC(n) asm volatile("s_waitcnt vmcnt(" #n ")" ::: "memory")
#define PHASE(P, MH, KS, RB, STG, VM) do {                                    \
    const _Float16* Ab = &lds[P][0][0];                                       \
    const _Float16* Bb = &lds[P][1][0];                                       \
    const int ax = (KS ? ax1 : ax0);                                          \
    f16x8 a[4];                                                               \
    _Pragma("unroll")                                                         \
    for (int m = 0; m < 4; ++m)                                               \
        a[m] = *(const f16x8*)&Ab[aRB + MH * 4096 + m * 1024 + ax];           \
    if (RB) {                                                                 \
        _Pragma("unroll")                                                     \
        for (int n = 0; n < 4; ++n)                                           \
            b[n] = *(const f16x8*)&Bb[bRB + n * 1024 + ax];                   \
    }                                                                         \
    STG                                                                       \
    __builtin_amdgcn_s_barrier();                                             \
    asm volatile("s_waitcnt lgkmcnt(0)" ::: "memory");                        \
    __builtin_amdgcn_s_setprio(1);                                            \
    _Pragma("unroll")                                                         \
    for (int m = 0; m < 4; ++m)                                               \
        _Pragma("unroll")                                                     \
        for (int n = 0; n < 4; ++n)                                           \
            acc[MH * 4 + m][n] = __builtin_amdgcn_mfma_f32_16x16x32_f16(      \
                a[m], b[n], acc[MH * 4 + m][n], 0, 0, 0);                     \
    __builtin_amdgcn_s_setprio(0);                                            \
    VM;                                                                       \
    __builtin_amdgcn_s_barrier();                                             \
} while (0)

#define TILE(P, TB, TA)                                                       \
    PHASE(P, 0, 0, 1,                                                         \
          { stB(P ^ 1, 0, TB); stB(P ^ 1, 1, TB);                             \
            stB(P ^ 1, 2, TB); stB(P ^ 1, 3, TB); }, VMC(6));                 \
    PHASE(P, 1, 0, 0, { stA(P ^ 1, 1, TB); stA(P ^ 1, 3, TB); }, );           \
    PHASE(P, 0, 1, 1, {;}, );                                                 \
    PHASE(P, 1, 1, 0, { stA(P, 0, TA); stA(P, 2, TA); }, VMC(4))

    // prologue (oldest->newest): A02(0), B0-3(0), A13(0) -> buf0; A02(1) -> buf1
    stA(0, 0, 0); stA(0, 2, 0);
    stB(0, 0, 0); stB(0, 1, 0); stB(0, 2, 0); stB(0, 3, 0);
    stA(0, 1, 0); stA(0, 3, 0);
    stA(1, 0, 1); stA(1, 2, 1);
    VMC(4);                        // forces A02(0)+B(0); allows A13(0)+A02(1)
    __builtin_amdgcn_s_barrier();

#pragma unroll 1
    for (int t = 0; t < NT_P - 1; t += 2) {
        int t3 = t + 3;
        if (t3 >= NT_P) t3 = 0;                    // wrap: dead-region stage
        TILE(0, t + 1, t + 2);
        TILE(1, t + 2, t3);
    }
    TILE(0, 0, 1);                                 // tile 64; stages wrap (dead)

#undef TILE
#undef PHASE
#undef VMC

    // epilogue: C/D layout col=lane&15, row=(lane>>4)*4+reg
#pragma unroll
    for (int mi = 0; mi < 8; ++mi) {
        const int row = arow0 + wr * 128 + mi * 16 + g * 4;
#pragma unroll
        for (int n = 0; n < 4; ++n) {
            const int col = brow0 + wc * 64 + n * 16 + fm;
            float* cp = C + (size_t)row * N_OUT + col;
#pragma unroll
            for (int r = 0; r < 4; ++r)
                cp[(size_t)r * N_OUT] = acc[mi][n][r];
        }
    }
}

// ---------------------------------------------------------------------------
// Naive fp32 fallback (ws too small)
// ---------------------------------------------------------------------------
__global__ void fb_t(const float* __restrict__ x, const float* __restrict__ Dm,
                     float* __restrict__ t) {
    int n = blockIdx.x, r = threadIdx.x;
    const float* xr = x + (size_t)n * K_IN;
    const float* dr = Dm + (size_t)r * K_IN;
    float s = 0.f;
    for (int k = 0; k < K_IN; k++) s += xr[k] * dr[k];
    t[n * RANK + r] = s;
}

__global__ void fb_main(const float* __restrict__ x, const float* __restrict__ scales,
                        const float* __restrict__ U, const int* __restrict__ Q,
                        const float* __restrict__ t, float* __restrict__ out) {
    size_t i = (size_t)blockIdx.x * 256 + threadIdx.x;
    int n = (int)(i >> 12), o = (int)(i & 4095);
    const float* xr = x + (size_t)n * K_IN;
    const int* qr = Q + (size_t)o * K_IN;
    float s = 0.f;
    for (int k = 0; k < K_IN; k++) s += xr[k] * (float)qr[k];
    float a = 0.f;
    const float* tr = t + (size_t)n * RANK;
    const float* ur = U + (size_t)o * RANK;
    for (int r = 0; r < RANK; r++) a += tr[r] * ur[r];
    out[i] = scales[o] * s + a;
}

// ---------------------------------------------------------------------------
extern "C" void kernel_launch(void* const* d_in, const int* in_sizes, int n_in,
                              void* d_out, int out_size, void* d_ws, size_t ws_size,
                              hipStream_t stream) {
    const float* x      = (const float*)d_in[0];
    const float* scales = (const float*)d_in[1];
    const float* U      = (const float*)d_in[2];
    const float* D      = (const float*)d_in[3];
    const int*   Q      = (const int*)d_in[4];
    float* out = (float*)d_out;

    const size_t SZ_XT  = (size_t)M_TOK * LDA_P * 2;
    const size_t SZ_WU  = (size_t)N_OUT * LDA_P * 2;
    const size_t SZ_D   = (size_t)RANK * K_IN * 2;
    const size_t SZ_T32 = (size_t)KSPLIT * M_TOK * RANK * 4;
    const size_t NEED   = SZ_XT + SZ_WU + SZ_D + SZ_T32;

    if (ws_size >= NEED) {
        char* w = (char*)d_ws;
        _Float16* XT  = (_Float16*)w; w += SZ_XT;
        _Float16* WU  = (_Float16*)w; w += SZ_WU;
        _Float16* Dh  = (_Float16*)w; w += SZ_D;
        float*    T32 = (float*)w;

        k_cvt_f32_f16<<<256, 256, 0, stream>>>((const float4*)D, (f16x4*)Dh,
                                               RANK * K_IN / 4);
        k_cvt_x<<<2048, 256, 0, stream>>>((const float4*)x, XT);
        k_t<<<dim3(M_TOK / 64, KSPLIT), 256, 0, stream>>>(XT, Dh, T32);
        k_reduce_t<<<M_TOK * RANK / 256, 256, 0, stream>>>(T32, XT);
        k_cvt_w8<<<N_OUT * K_IN / 8 / 256, 256, 0, stream>>>((const int4*)Q,
                                                             scales, WU);
        k_cvt_u<<<N_OUT * RANK / 8 / 256, 256, 0, stream>>>(U, WU);
        k_main<<<512, 512, 0, stream>>>(XT, WU, out);
    } else {
        float* t32 = (float*)d_ws;
        fb_t<<<M_TOK, RANK, 0, stream>>>(x, D, t32);
        fb_main<<<(int)((size_t)M_TOK * N_OUT / 256), 256, 0, stream>>>(
            x, scales, U, Q, t32, out);
    }
}